// Round 12
// baseline (239.683 us; speedup 1.0000x reference)
//
#include <hip/hip_runtime.h>
#include <math.h>

typedef __attribute__((ext_vector_type(4)))  float f32x4;
typedef __attribute__((ext_vector_type(16))) float f32x16;
typedef __attribute__((ext_vector_type(8)))  short bf16x8;

#define NB   64
#define CD   128
#define TD   2048
#define QBLK 128             // per block (4 waves x 32 rows)
#define KVB  32
#define NKV  (TD / KVB)      // 64
#define NQT  (TD / QBLK)     // 16

#define TILE_B   8192        // K tile: [cblk 0..15][s 0..31] 16B ; V tile: [sblk 0..3][c 0..127] 16B
#define VBASE    ((size_t)NB * NKV * TILE_B)   // 33,554,432 (total ws = 64 MB)

__device__ __forceinline__ short f2bf(float f) {
    union { float f; unsigned u; } x; x.f = f;
    unsigned r = x.u + 0x7FFFu + ((x.u >> 16) & 1u);   // RNE
    return (short)(r >> 16);
}

// ---------------------------------------------------------------------------
// Prepass: K -> plane-major transposed tiles [cblk][s][8c], V -> plane-major
// natural tiles [sblk][c][8s]. Fragment loads then hit per-lane 16B chunks.
// (Unchanged from R7.)
// ---------------------------------------------------------------------------
__global__ __launch_bounds__(256)
void prepass(const float* __restrict__ qkv, char* __restrict__ ws)
{
    int blk  = blockIdx.x;            // 64 b * 64 (kind,sb)
    int b    = blk >> 6;
    int rem  = blk & 63;
    int kind = rem >> 5;              // 0=K, 1=V
    int sb   = rem & 31;              // 64-row source slab -> 2 tiles
    int s0   = sb * 64;
    int tid  = threadIdx.x;
    const float* src = qkv + ((size_t)b * 3 + 1 + kind) * CD * TD;

    if (kind == 0) {
        // K transpose: stage [s'][c] in LDS, emit plane-major tiles
        __shared__ short Tl[64][CD + 8];
        int su = (tid & 15) * 4;
        int cb = 4 * (tid >> 4);
        #pragma unroll
        for (int it = 0; it < 2; ++it) {
            int c0 = cb + 64 * it;
            f32x4 r0 = *(const f32x4*)&src[(size_t)(c0 + 0) * TD + s0 + su];
            f32x4 r1 = *(const f32x4*)&src[(size_t)(c0 + 1) * TD + s0 + su];
            f32x4 r2 = *(const f32x4*)&src[(size_t)(c0 + 2) * TD + s0 + su];
            f32x4 r3 = *(const f32x4*)&src[(size_t)(c0 + 3) * TD + s0 + su];
            #pragma unroll
            for (int s = 0; s < 4; ++s) {
                short4 w;
                w.x = f2bf(r0[s]); w.y = f2bf(r1[s]);
                w.z = f2bf(r2[s]); w.w = f2bf(r3[s]);
                *(short4*)&Tl[su + s][c0] = w;
            }
        }
        __syncthreads();
        char* kt0 = ws + ((size_t)b * NKV + 2 * sb) * TILE_B;
        #pragma unroll
        for (int it = 0; it < 4; ++it) {
            int row = (tid >> 4) + 16 * it;     // 0..63 source s
            int p   = tid & 15;                 // cblk
            *(f32x4*)(kt0 + (row >> 5) * TILE_B + p * 512 + (row & 31) * 16)
                = *(const f32x4*)&Tl[row][p * 8];
        }
    } else {
        // V: tile[sblk][c][8 s-values], contiguous 16B stores per (c, chunk)
        char* vt0 = ws + VBASE + ((size_t)b * NKV + 2 * sb) * TILE_B;
        int c  = tid >> 1;
        int hh = tid & 1;
        #pragma unroll
        for (int i = 0; i < 4; ++i) {
            int q = 4 * hh + i;                 // 8B-pair chunk 0..7 over 64 s
            f32x4 a0 = *(const f32x4*)&src[(size_t)c * TD + s0 + q * 8];
            f32x4 a1 = *(const f32x4*)&src[(size_t)c * TD + s0 + q * 8 + 4];
            bf16x8 w;
            w[0] = f2bf(a0[0]); w[1] = f2bf(a0[1]); w[2] = f2bf(a0[2]); w[3] = f2bf(a0[3]);
            w[4] = f2bf(a1[0]); w[5] = f2bf(a1[1]); w[6] = f2bf(a1[2]); w[7] = f2bf(a1[3]);
            *(bf16x8*)(vt0 + (q >> 2) * TILE_B + (q & 3) * 2048 + c * 16) = w;
        }
    }
}

// ---------------------------------------------------------------------------
// Attention: NO LDS, NO barriers. Each wave loads its K/V MFMA fragments
// directly from the plane-major global tiles (L2/L3-resident). K frags
// ping-pong with distance-2 prefetch; V frags issued at iter top, consumed
// after QK+softmax. Fully independent waves.
// ---------------------------------------------------------------------------
__global__ __launch_bounds__(256, 2)
void attn_fwd(const float* __restrict__ qkv, const char* __restrict__ ws,
              float* __restrict__ out)
{
    // XCD-bijective decode (grid 1024, 256t blocks: proven L2 locality)
    int i    = blockIdx.x;            // 1024 workgroups
    int xcd  = i & 7;
    int slot = i >> 3;                // 0..127
    int b    = xcd * 8 + (slot >> 4);
    int tt   = slot & 15;
    int t0   = tt * QBLK;

    int tid  = threadIdx.x;
    int wid  = tid >> 6;              // wave 0..3: rows [t0+32*wid, +32)
    int lane = tid & 63;
    int h    = lane >> 5;             // k-half
    int tcol = lane & 31;

    const char*  ktb = ws + (size_t)b * NKV * TILE_B;
    const char*  vtb = ws + VBASE + (size_t)b * NKV * TILE_B;
    const float* qb  = qkv + (size_t)b * 3 * CD * TD;

    int kbase = h * 512  + tcol * 16; // K frag: + kt*1024 (+ sb*TILE_B)
    int vbase = h * 2048 + tcol * 16; // V frag: + (f>>2)*4096 + (f&3)*512

    // ---- Q fragments fp32->bf16, scale*log2e folded. B[n=t][k=c] ----
    const float SCALE2 = 0.12751743f;   // log2(e)/sqrt(128)
    int tq = t0 + 32 * wid + tcol;
    bf16x8 qf[8];
    #pragma unroll
    for (int kt = 0; kt < 8; ++kt)
        #pragma unroll
        for (int j = 0; j < 8; ++j)
            qf[kt][j] = f2bf(qb[(size_t)(16 * kt + 8 * h + j) * TD + tq] * SCALE2);

    // ---- prologue: K(0) -> kA, K(1) -> kB ----
    bf16x8 kA[8], kB[8];
    #pragma unroll
    for (int kt = 0; kt < 8; ++kt)
        kA[kt] = *(const bf16x8*)(ktb + kbase + kt * 1024);
    #pragma unroll
    for (int kt = 0; kt < 8; ++kt)
        kB[kt] = *(const bf16x8*)(ktb + TILE_B + kbase + kt * 1024);

    f32x16 o[4];
    #pragma unroll
    for (int mt = 0; mt < 4; ++mt) o[mt] = (f32x16)(0.0f);
    float m = -1e30f, lsum = 0.0f;    // per-lane (column tq) state

    // ITER(sb): V(sb)->vf issued first; QK from kc (loaded 2 iters ago);
    // then kc <- K(sb+2); softmax; PV from vf.
    auto ITER = [&](int sb, bf16x8 (&kc)[8]) __attribute__((always_inline))
    {
        // ---- issue V(sb) fragment loads (consumed after QK+softmax) ----
        const char* vg = vtb + (size_t)sb * TILE_B;
        bf16x8 vf[8];
        #pragma unroll
        for (int f = 0; f < 8; ++f)
            vf[f] = *(const bf16x8*)(vg + vbase + (f >> 2) * 4096 + (f & 3) * 512);

        // ---- QK^T swapped: D[m=s][n=t] = sum_c K[s][c] Q[c][t] ----
        f32x16 acc = (f32x16)(0.0f);
        __builtin_amdgcn_s_setprio(1);
        #pragma unroll
        for (int kt = 0; kt < 8; ++kt)
            acc = __builtin_amdgcn_mfma_f32_32x32x16_bf16(kc[kt], qf[kt], acc, 0, 0, 0);
        __builtin_amdgcn_s_setprio(0);

        // ---- kc now dead: prefetch K(sb+2) into it (distance-2 cover) ----
        {
            int nk = (sb + 2 < NKV) ? sb + 2 : NKV - 1;
            const char* kg = ktb + (size_t)nk * TILE_B;
            #pragma unroll
            for (int kt = 0; kt < 8; ++kt)
                kc[kt] = *(const bf16x8*)(kg + kbase + kt * 1024);
        }

        // ---- softmax (exp2 domain), per-lane scalar state ----
        float px0 = fmaxf(fmaxf(acc[0], acc[4]),  fmaxf(acc[8],  acc[12]));
        float px1 = fmaxf(fmaxf(acc[1], acc[5]),  fmaxf(acc[9],  acc[13]));
        float px2 = fmaxf(fmaxf(acc[2], acc[6]),  fmaxf(acc[10], acc[14]));
        float px3 = fmaxf(fmaxf(acc[3], acc[7]),  fmaxf(acc[11], acc[15]));
        float pm = fmaxf(fmaxf(px0, px1), fmaxf(px2, px3));

        // defer-max: partial check equivalent to full under __all (lane^32 pair)
        if (!__all(pm <= m + 8.0f)) {
            float rm = fmaxf(pm, __shfl_xor(pm, 32, 64));
            rm = fmaxf(m, rm);
            float cr = exp2f(m - rm);
            m = rm;
            lsum *= cr;
            #pragma unroll
            for (int mt = 0; mt < 4; ++mt)
                #pragma unroll
                for (int r = 0; r < 16; ++r)
                    o[mt][r] *= cr;
        }
        float s0a = 0.f, s1a = 0.f, s2a = 0.f, s3a = 0.f;
        #pragma unroll
        for (int r = 0; r < 16; r += 4) {
            acc[r + 0] = exp2f(acc[r + 0] - m);
            acc[r + 1] = exp2f(acc[r + 1] - m);
            acc[r + 2] = exp2f(acc[r + 2] - m);
            acc[r + 3] = exp2f(acc[r + 3] - m);
            s0a += acc[r + 0];
            s1a += acc[r + 1];
            s2a += acc[r + 2];
            s3a += acc[r + 3];
        }
        lsum += (s0a + s1a) + (s2a + s3a);

        // ---- P^T -> PV B-frags in-register: cvt_pk + lane^32 exchange ----
        unsigned pfr[2][4];
        #pragma unroll
        for (int e = 0; e < 2; ++e) {
            unsigned k0_, k1_, k2_, k3_;
            asm("v_cvt_pk_bf16_f32 %0, %1, %2" : "=v"(k0_) : "v"(acc[8*e+0]), "v"(acc[8*e+1]));
            asm("v_cvt_pk_bf16_f32 %0, %1, %2" : "=v"(k1_) : "v"(acc[8*e+2]), "v"(acc[8*e+3]));
            asm("v_cvt_pk_bf16_f32 %0, %1, %2" : "=v"(k2_) : "v"(acc[8*e+4]), "v"(acc[8*e+5]));
            asm("v_cvt_pk_bf16_f32 %0, %1, %2" : "=v"(k3_) : "v"(acc[8*e+6]), "v"(acc[8*e+7]));
            unsigned sA = h ? k0_ : k2_;
            unsigned sB = h ? k1_ : k3_;
            unsigned r0 = (unsigned)__shfl_xor((int)sA, 32, 64);
            unsigned r1 = (unsigned)__shfl_xor((int)sB, 32, 64);
            pfr[e][0] = h ? r0 : k0_;
            pfr[e][1] = h ? r1 : k1_;
            pfr[e][2] = h ? k2_ : r0;
            pfr[e][3] = h ? k3_ : r1;
        }

        // ---- PV swapped: D[m=c][n=t] = sum_s V[c][s] P^T[s][t] ----
        __builtin_amdgcn_s_setprio(1);
        #pragma unroll
        for (int kt2 = 0; kt2 < 2; ++kt2) {
            union { unsigned u[4]; bf16x8 v; } pw;
            pw.u[0] = pfr[kt2][0]; pw.u[1] = pfr[kt2][1];
            pw.u[2] = pfr[kt2][2]; pw.u[3] = pfr[kt2][3];
            #pragma unroll
            for (int mt = 0; mt < 4; ++mt)
                o[mt] = __builtin_amdgcn_mfma_f32_32x32x16_bf16(vf[kt2 * 4 + mt], pw.v, o[mt], 0, 0, 0);
        }
        __builtin_amdgcn_s_setprio(0);
    };

    #pragma unroll 1
    for (int s2 = 0; s2 < NKV; s2 += 2) {
        ITER(s2,     kA);
        ITER(s2 + 1, kB);
    }

    // ---- epilogue: finish denominator across lane^32 pair, store out[c][t] ----
    lsum += __shfl_xor(lsum, 32, 64);
    float inv = 1.0f / lsum;
    float* ob = out + (size_t)b * CD * TD;
    #pragma unroll
    for (int mt = 0; mt < 4; ++mt)
        #pragma unroll
        for (int r = 0; r < 16; ++r) {
            int c = 32 * mt + (r & 3) + 8 * (r >> 2) + 4 * h;
            ob[(size_t)c * TD + tq] = o[mt][r] * inv;
        }
}

extern "C" void kernel_launch(void* const* d_in, const int* in_sizes, int n_in,
                              void* d_out, int out_size, void* d_ws, size_t ws_size,
                              hipStream_t stream)
{
    const float* qkv = (const float*)d_in[0];
    float* out = (float*)d_out;
    char* ws = (char*)d_ws;
    prepass<<<dim3(NB * 64), 256, 0, stream>>>(qkv, ws);                   // 4096 wgs
    attn_fwd<<<dim3(NB * NQT), 256, 0, stream>>>(qkv, ws, out);            // 1024 wgs
}